// Round 13
// baseline (1150.375 us; speedup 1.0000x reference)
//
#include <hip/hip_runtime.h>
#include <hip/hip_bf16.h>

#define N_ 8192
#define T_ 12
#define B_ 2
#define FIN_ 8
#define HID_ 16
#define CGSZ 131072   // one column-group (16 cols) frag block: 256 kb * 64 lanes * 8 elems

typedef short s8v __attribute__((ext_vector_type(8)));
typedef float f4v __attribute__((ext_vector_type(4)));

__device__ __forceinline__ float sigmoidf_(float x){ return 1.f/(1.f + __expf(-x)); }

#define MFMA16(a,b,c) __builtin_amdgcn_mfma_f32_16x16x32_bf16(a,b,c,0,0,0)

// global -> LDS direct DMA, 16B per lane. LDS dest must be wave-uniform base;
// HW adds lane*16. Global src is the per-lane address.
#define GLDS16(gsrc, ldst) \
  __builtin_amdgcn_global_load_lds((const __attribute__((address_space(1))) void*)(gsrc), \
                                   (__attribute__((address_space(3))) void*)(ldst), 16, 0, 0)

// ---------------- prep: L fp32 -> bf16 fragment-major ----------------
__global__ __launch_bounds__(256) void build_Lp_kernel(const float* __restrict__ L,
                                                       __hip_bfloat16* __restrict__ Lp){
  __shared__ unsigned short tile[16][264];
  const int cb = blockIdx.x;   // 0..31
  const int rt = blockIdx.y;   // 0..511
  const int tid = threadIdx.x;
  #pragma unroll
  for (int i = 0; i < 4; ++i){
    int flat = i*256 + tid;
    int r  = flat >> 6;
    int c4 = flat & 63;
    float4 v = *(const float4*)(L + (long)(rt*16 + r)*N_ + cb*256 + c4*4);
    tile[r][c4*4+0] = __bfloat16_as_ushort(__float2bfloat16(v.x));
    tile[r][c4*4+1] = __bfloat16_as_ushort(__float2bfloat16(v.y));
    tile[r][c4*4+2] = __bfloat16_as_ushort(__float2bfloat16(v.z));
    tile[r][c4*4+3] = __bfloat16_as_ushort(__float2bfloat16(v.w));
  }
  __syncthreads();
  #pragma unroll
  for (int j = 0; j < 2; ++j){
    int flat = j*256 + tid;
    int kbl = flat >> 6;
    int l   = flat & 63;
    int lid = l & 15, g = l >> 4;
    uint4 frag = *(const uint4*)&tile[lid][kbl*32 + g*8];
    *(uint4*)(Lp + (((long)rt*256 + cb*8 + kbl)*64 + l)*8) = frag;
  }
}

// ---------------- prep: X (all t) and h0 -> bf16 frag-major (merged) ----------------
__global__ __launch_bounds__(256) void pack_xh_kernel(const float* __restrict__ X,
                                                      const float* __restrict__ H,
                                                      __hip_bfloat16* __restrict__ XTf,
                                                      __hip_bfloat16* __restrict__ hTf){
  if (blockIdx.x < 768){
    const int t = blockIdx.x >> 6;
    int flat = (blockIdx.x & 63)*256 + threadIdx.x;   // 0..16383
    int l = flat & 63, kb = flat >> 6;
    int lid = l & 15, g = l >> 4;
    int b = lid >> 3, f = lid & 7;
    int n0 = kb*32 + g*8;
    unsigned short u[8];
    #pragma unroll
    for (int e = 0; e < 8; ++e)
      u[e] = __bfloat16_as_ushort(__float2bfloat16(
          X[(((long)(b*T_ + t))*N_ + n0 + e)*FIN_ + f]));
    *(uint4*)(XTf + ((long)t*CGSZ + ((long)kb*64 + l)*8)) = *(uint4*)u;
  } else {
    int flat = (blockIdx.x - 768)*256 + threadIdx.x;  // 0..32767
    int l = flat & 63, kb = (flat >> 6) & 255, b = flat >> 14;
    int lid = l & 15, g = l >> 4;
    int n0 = kb*32 + g*8;
    unsigned short u[8];
    #pragma unroll
    for (int e = 0; e < 8; ++e)
      u[e] = __bfloat16_as_ushort(__float2bfloat16(
          H[((long)b*N_ + n0 + e)*HID_ + lid]));
    *(uint4*)(hTf + ((long)b*CGSZ + ((long)kb*64 + l)*8)) = *(uint4*)u;
  }
}

// ======== LDS-ring MFMA core (shared body via macro; per-wave ring, no barriers) ========
// ring[w][slot][stream][lane]: stream 0=A0 1=A1 2=B0 3=B1 4=B2, 1KB each.
// depth 3: consume slot kk%3 while stages kk+1,kk+2 are in DMA flight (vmcnt 10).
#define MM_RING_CORE(RING, A0p, A1p, P0p, P1p, P2p)                              \
  f4v a00={0,0,0,0}, a01={0,0,0,0}, a02={0,0,0,0};                               \
  f4v a10={0,0,0,0}, a11={0,0,0,0}, a12={0,0,0,0};                               \
  _Pragma("unroll")                                                              \
  for (int s = 0; s < 3; ++s){                                                   \
    GLDS16(A0p + (long)s*64, &RING[w][s][0][0]);                                 \
    GLDS16(A1p + (long)s*64, &RING[w][s][1][0]);                                 \
    GLDS16(P0p + (long)s*64, &RING[w][s][2][0]);                                 \
    GLDS16(P1p + (long)s*64, &RING[w][s][3][0]);                                 \
    GLDS16(P2p + (long)s*64, &RING[w][s][4][0]);                                 \
  }                                                                              \
  _Pragma("unroll")                                                              \
  for (int kk = 0; kk < 29; ++kk){                                               \
    const int s = kk % 3;                                                        \
    asm volatile("s_waitcnt vmcnt(10)" ::: "memory");                            \
    s8v a0 = RING[w][s][0][lane];                                                \
    s8v a1 = RING[w][s][1][lane];                                                \
    s8v b0 = RING[w][s][2][lane];                                                \
    s8v b1 = RING[w][s][3][lane];                                                \
    s8v b2 = RING[w][s][4][lane];                                                \
    asm volatile("s_waitcnt lgkmcnt(0)" ::: "memory");                           \
    GLDS16(A0p + (long)(kk+3)*64, &RING[w][s][0][0]);                            \
    GLDS16(A1p + (long)(kk+3)*64, &RING[w][s][1][0]);                            \
    GLDS16(P0p + (long)(kk+3)*64, &RING[w][s][2][0]);                            \
    GLDS16(P1p + (long)(kk+3)*64, &RING[w][s][3][0]);                            \
    GLDS16(P2p + (long)(kk+3)*64, &RING[w][s][4][0]);                            \
    a00 = MFMA16(a0,b0,a00); a01 = MFMA16(a0,b1,a01); a02 = MFMA16(a0,b2,a02);   \
    a10 = MFMA16(a1,b0,a10); a11 = MFMA16(a1,b1,a11); a12 = MFMA16(a1,b2,a12);   \
  }                                                                              \
  _Pragma("unroll")                                                              \
  for (int kk = 29; kk < 32; ++kk){                                              \
    const int s = kk % 3;                                                        \
    if (kk == 29) { asm volatile("s_waitcnt vmcnt(10)" ::: "memory"); }          \
    else if (kk == 30) { asm volatile("s_waitcnt vmcnt(5)" ::: "memory"); }      \
    else { asm volatile("s_waitcnt vmcnt(0)" ::: "memory"); }                    \
    s8v a0 = RING[w][s][0][lane];                                                \
    s8v a1 = RING[w][s][1][lane];                                                \
    s8v b0 = RING[w][s][2][lane];                                                \
    s8v b1 = RING[w][s][3][lane];                                                \
    s8v b2 = RING[w][s][4][lane];                                                \
    asm volatile("s_waitcnt lgkmcnt(0)" ::: "memory");                           \
    a00 = MFMA16(a0,b0,a00); a01 = MFMA16(a0,b1,a01); a02 = MFMA16(a0,b2,a02);   \
    a10 = MFMA16(a1,b0,a10); a11 = MFMA16(a1,b1,a11); a12 = MFMA16(a1,b2,a12);   \
  }                                                                              \
  /* red[w] unioned into wave w's own ring region (loop done, data consumed) */  \
  {                                                                              \
    float* rw = (float*)&RING[w][0][0][0];                                       \
    *(f4v*)&rw[((0*3+0)*64 + lane)*4] = a00;                                     \
    *(f4v*)&rw[((0*3+1)*64 + lane)*4] = a01;                                     \
    *(f4v*)&rw[((0*3+2)*64 + lane)*4] = a02;                                     \
    *(f4v*)&rw[((1*3+0)*64 + lane)*4] = a10;                                     \
    *(f4v*)&rw[((1*3+1)*64 + lane)*4] = a11;                                     \
    *(f4v*)&rw[((1*3+2)*64 + lane)*4] = a12;                                     \
  }

// ---------------- pass 1: [u(32) | p(16)] = L @ [h | x_t]  (+ bf16 frag out) ----------------
__global__ __launch_bounds__(512) void mm_pass1_kernel(
    const __hip_bfloat16* __restrict__ Lp,
    const __hip_bfloat16* __restrict__ hTf,
    const __hip_bfloat16* __restrict__ XTft,
    __hip_bfloat16* __restrict__ y1f,
    float* __restrict__ u_, float* __restrict__ p_)
{
  __shared__ s8v ring[8][3][5][64];       // 122880 B (ring; red[w] unioned per wave)
  const int tid = threadIdx.x, w = tid >> 6, lane = tid & 63, blk = blockIdx.x;
  const int kb0 = w*32;
  const s8v* A0p = (const s8v*)(const void*)Lp + ((long)(blk*2+0)*256 + kb0)*64 + lane;
  const s8v* A1p = (const s8v*)(const void*)Lp + ((long)(blk*2+1)*256 + kb0)*64 + lane;
  const s8v* P0p = (const s8v*)(const void*)hTf + (long)kb0*64 + lane;
  const s8v* P1p = (const s8v*)(const void*)(hTf + CGSZ) + (long)kb0*64 + lane;
  const s8v* P2p = (const s8v*)(const void*)XTft + (long)kb0*64 + lane;

  MM_RING_CORE(ring, A0p, A1p, P0p, P1p, P2p)

  __syncthreads();
  for (int v = tid; v < 1536; v += 512){
    int rtl = (v >= 768) ? 1 : 0;
    int rem = v - rtl*768;
    int cgI = rem >> 8, r255 = rem & 255;
    int lid = r255 & 15, r = r255 >> 4;
    int g = r >> 2, j = r & 3;
    float s = 0.f;
    #pragma unroll
    for (int ww = 0; ww < 8; ++ww){
      const float* rw = (const float*)&ring[ww][0][0][0];
      s += rw[((rtl*3 + cgI)*64 + g*16 + lid)*4 + j];
    }
    int n = blk*32 + rtl*16 + r;
    long o = (((long)cgI*256 + (n>>5))*64 + ((n>>3)&3)*16 + lid)*8 + (n&7);
    y1f[o] = __float2bfloat16(s);
    if (cgI < 2) u_[((long)cgI*N_ + n)*HID_ + lid] = s;
    else         p_[((long)(lid>>3)*N_ + n)*FIN_ + (lid&7)] = s;
  }
}

// ---------------- pass 2 + fused gates ----------------
__global__ __launch_bounds__(512) void mm_pass2_gate_kernel(
    const __hip_bfloat16* __restrict__ Lp,
    const __hip_bfloat16* __restrict__ y1f,
    const float* __restrict__ X,
    const float* __restrict__ H0, const float* __restrict__ C0,
    const float* __restrict__ Wx, const float* __restrict__ Wh,
    const float* __restrict__ bx, const float* __restrict__ bh,
    const float* __restrict__ wc, const float* __restrict__ bg,
    const float* __restrict__ u_, const float* __restrict__ p_,
    float* __restrict__ out, float* __restrict__ hs, float* __restrict__ cs,
    __hip_bfloat16* __restrict__ hTf, int t)
{
  __shared__ s8v ring[8][3][5][64];       // 122880 B
  __shared__ float uv[48][32];            //   6144 B
  __shared__ float wlds[4848];            //  19392 B
  const int tid = threadIdx.x, w = tid >> 6, lane = tid & 63, blk = blockIdx.x;

  // stage gate weights FIRST (their vmcnt events complete before the ring's;
  // any extra outstanding only lengthens counted waits -> safe).
  for (int i = tid; i < 1536; i += 512) wlds[i] = Wx[(long)t*1536 + i];
  for (int i = tid; i < 3072; i += 512) wlds[1536 + i] = Wh[(long)t*3072 + i];
  if (tid < 64){
    wlds[4608 + tid] = bx[t*64 + tid];
    wlds[4672 + tid] = bh[t*64 + tid];
    wlds[4736 + tid] = bg[t*64 + tid];
  }
  if (tid < 48) wlds[4800 + tid] = wc[t*48 + tid];

  const int kb0 = w*32;
  const s8v* A0p = (const s8v*)(const void*)Lp + ((long)(blk*2+0)*256 + kb0)*64 + lane;
  const s8v* A1p = (const s8v*)(const void*)Lp + ((long)(blk*2+1)*256 + kb0)*64 + lane;
  const s8v* P0p = (const s8v*)(const void*)y1f + (long)kb0*64 + lane;
  const s8v* P1p = (const s8v*)(const void*)(y1f + CGSZ) + (long)kb0*64 + lane;
  const s8v* P2p = (const s8v*)(const void*)(y1f + 2*CGSZ) + (long)kb0*64 + lane;

  MM_RING_CORE(ring, A0p, A1p, P0p, P1p, P2p)

  __syncthreads();
  for (int v = tid; v < 1536; v += 512){
    int rtl = (v >= 768) ? 1 : 0;
    int rem = v - rtl*768;
    int cgI = rem >> 8, r255 = rem & 255;
    int lid = r255 & 15, r = r255 >> 4;
    int g = r >> 2, j = r & 3;
    float s = 0.f;
    #pragma unroll
    for (int ww = 0; ww < 8; ++ww){
      const float* rw = (const float*)&ring[ww][0][0][0];
      s += rw[((rtl*3 + cgI)*64 + g*16 + lid)*4 + j];
    }
    uv[cgI*16 + lid][rtl*16 + r] = s;
  }
  __syncthreads();

  // gates: 1024 items (2 batch x 32 rows x 16 hid) over 512 threads
  #pragma unroll
  for (int it = 0; it < 2; ++it){
    int item = it*512 + tid;
    int gb = item >> 9, rr = (item >> 4) & 31, gh = item & 15;
    int n_g = blk*32 + rr;
    const float* xp = X + (((long)(gb*T_ + t))*N_ + n_g)*FIN_;
    const float* hp = (t==0) ? (H0 + ((long)gb*N_ + n_g)*HID_)
                             : (hs + (((long)(t-1)*B_ + gb)*N_ + n_g)*HID_);
    const float* cp = (t==0) ? (C0 + ((long)gb*N_ + n_g)*HID_)
                             : (cs + (((long)(t-1)*B_ + gb)*N_ + n_g)*HID_);
    const float* up = u_ + ((long)gb*N_ + n_g)*HID_;
    const float* pp = p_ + ((long)gb*N_ + n_g)*FIN_;

    float pre0 = wlds[4608 +  0 + gh] + wlds[4672 +  0 + gh] + wlds[4736 +  0 + gh];
    float pre1 = wlds[4608 + 16 + gh] + wlds[4672 + 16 + gh] + wlds[4736 + 16 + gh];
    float pre2 = wlds[4608 + 32 + gh] + wlds[4672 + 32 + gh] + wlds[4736 + 32 + gh];
    float pre3 = wlds[4608 + 48 + gh] + wlds[4672 + 48 + gh] + wlds[4736 + 48 + gh];
    #pragma unroll
    for (int f = 0; f < 8; ++f){
      float t0 = xp[f];
      float t1 = pp[f];
      float t2 = 2.f*uv[32 + gb*8 + f][rr] - t0;
      pre0 += t0*wlds[((0*3+0)*8+f)*16+gh] + t1*wlds[((0*3+1)*8+f)*16+gh] + t2*wlds[((0*3+2)*8+f)*16+gh];
      pre1 += t0*wlds[((1*3+0)*8+f)*16+gh] + t1*wlds[((1*3+1)*8+f)*16+gh] + t2*wlds[((1*3+2)*8+f)*16+gh];
      pre2 += t0*wlds[((2*3+0)*8+f)*16+gh] + t1*wlds[((2*3+1)*8+f)*16+gh] + t2*wlds[((2*3+2)*8+f)*16+gh];
      pre3 += t0*wlds[((3*3+0)*8+f)*16+gh] + t1*wlds[((3*3+1)*8+f)*16+gh] + t2*wlds[((3*3+2)*8+f)*16+gh];
    }
    #pragma unroll
    for (int j = 0; j < 16; ++j){
      float t0 = hp[j];
      float t1 = up[j];
      float t2 = 2.f*uv[gb*16 + j][rr] - t0;
      pre0 += t0*wlds[1536+((0*3+0)*16+j)*16+gh] + t1*wlds[1536+((0*3+1)*16+j)*16+gh] + t2*wlds[1536+((0*3+2)*16+j)*16+gh];
      pre1 += t0*wlds[1536+((1*3+0)*16+j)*16+gh] + t1*wlds[1536+((1*3+1)*16+j)*16+gh] + t2*wlds[1536+((1*3+2)*16+j)*16+gh];
      pre2 += t0*wlds[1536+((2*3+0)*16+j)*16+gh] + t1*wlds[1536+((2*3+1)*16+j)*16+gh] + t2*wlds[1536+((2*3+2)*16+j)*16+gh];
      pre3 += t0*wlds[1536+((3*3+0)*16+j)*16+gh] + t1*wlds[1536+((3*3+1)*16+j)*16+gh] + t2*wlds[1536+((3*3+2)*16+j)*16+gh];
    }
    float cc = cp[gh];
    float ig = sigmoidf_(pre0 + wlds[4800 +  0 + gh]*cc);
    float fg = sigmoidf_(pre1 + wlds[4800 + 16 + gh]*cc);
    float cnew = fg*cc + ig*tanhf(pre2);
    float og = sigmoidf_(pre3 + wlds[4800 + 32 + gh]*cnew);
    float hn = og*tanhf(cnew);
    hs [(((long)t*B_ + gb)*N_ + n_g)*HID_ + gh] = hn;
    cs [(((long)t*B_ + gb)*N_ + n_g)*HID_ + gh] = cnew;
    out[(((long)gb*T_ + t)*N_ + n_g)*HID_ + gh] = hn;
    const int kb = n_g >> 5, gg = (n_g >> 3) & 3, e = n_g & 7;
    hTf[(((long)gb*256 + kb)*64 + gg*16 + gh)*8 + e] = __float2bfloat16(hn);
  }
}

extern "C" void kernel_launch(void* const* d_in, const int* in_sizes, int n_in,
                              void* d_out, int out_size, void* d_ws, size_t ws_size,
                              hipStream_t stream)
{
  const float* X  = (const float*)d_in[0];
  const float* L  = (const float*)d_in[1];
  const float* H  = (const float*)d_in[2];
  const float* C  = (const float*)d_in[3];
  const float* Wx = (const float*)d_in[4];
  const float* Wh = (const float*)d_in[5];
  const float* bx = (const float*)d_in[6];
  const float* bh = (const float*)d_in[7];
  const float* wc = (const float*)d_in[8];
  const float* bg = (const float*)d_in[9];

  float* out = (float*)d_out;
  float* hs  = out + (long)B_*T_*N_*HID_;
  float* cs  = hs  + (long)T_*B_*N_*HID_;

  const size_t NEEDED = 140247040;
  if (ws_size < NEEDED) return;
  char* ws = (char*)d_ws;
  __hip_bfloat16* Lp  = (__hip_bfloat16*)(ws);                   // 128 MiB frag-major L
  __hip_bfloat16* XTf = (__hip_bfloat16*)(ws + 134217728);       // 3 MiB   [12][CGSZ]
  __hip_bfloat16* hTf = (__hip_bfloat16*)(ws + 137363456);       // 512 KiB [2][CGSZ]
  __hip_bfloat16* y1f = (__hip_bfloat16*)(ws + 137887744);       // 768 KiB [3][CGSZ]
  float* u_ = (float*)(ws + 138674176);                          // 1 MiB   [2][8192][16]
  float* p_ = (float*)(ws + 139722752);                          // 512 KiB [2][8192][8]

  build_Lp_kernel<<<dim3(32,512), 256, 0, stream>>>(L, Lp);
  pack_xh_kernel <<<896, 256, 0, stream>>>(X, H, XTf, hTf);

  for (int t = 0; t < T_; ++t){
    mm_pass1_kernel<<<256, 512, 0, stream>>>(Lp, hTf, XTf + (long)t*CGSZ,
                                             y1f, u_, p_);
    mm_pass2_gate_kernel<<<256, 512, 0, stream>>>(Lp, y1f, X, H, C,
                                                  Wx, Wh, bx, bh, wc, bg,
                                                  u_, p_, out, hs, cs, hTf, t);
  }
}

// Round 14
// 1066.793 us; speedup vs baseline: 1.0783x; 1.0783x over previous
//
#include <hip/hip_runtime.h>
#include <hip/hip_bf16.h>

#define N_ 8192
#define T_ 12
#define B_ 2
#define FIN_ 8
#define HID_ 16
#define CGSZ 131072   // one column-group (16 cols) frag block: 256 kb * 64 lanes * 8 elems

typedef short s8v __attribute__((ext_vector_type(8)));
typedef float f4v __attribute__((ext_vector_type(4)));
typedef unsigned u32x4 __attribute__((ext_vector_type(4)));

__device__ __forceinline__ float sigmoidf_(float x){ return 1.f/(1.f + __expf(-x)); }

#define MFMA16(a,b,c) __builtin_amdgcn_mfma_f32_16x16x32_bf16(a,b,c,0,0,0)

// 128-bit buffer resource descriptor: base, stride=0, num_records=bytes, raw dword.
__device__ __forceinline__ u32x4 make_srsrc(const void* p, unsigned bytes){
  unsigned long a = (unsigned long)p;
  u32x4 r;
  r.x = (unsigned)a;
  r.y = (unsigned)(a >> 32) & 0xFFFFu;
  r.z = bytes;
  r.w = 0x00020000u;
  return r;
}

// A-stream load: sc1 -> stream past L2 (don't evict shared B), still allocates L3.
#define BLOAD_A(dst, rsrc, voff) \
  asm volatile("buffer_load_dwordx4 %0, %1, %2, 0 offen sc1" \
               : "=v"(dst) : "v"(voff), "s"(rsrc) : "memory")
// B-stream load: default policy (L2-cacheable).
#define BLOAD_B(dst, rsrc, voff) \
  asm volatile("buffer_load_dwordx4 %0, %1, %2, 0 offen" \
               : "=v"(dst) : "v"(voff), "s"(rsrc) : "memory")
#define WAITV(n) do { asm volatile("s_waitcnt vmcnt(" #n ")" ::: "memory"); \
                      __builtin_amdgcn_sched_barrier(0); } while(0)

// ---------------- prep: L fp32 -> bf16 fragment-major ----------------
// Lp[((rt*256 + kb)*64 + l)*8 + e] = bf16( L[rt*16 + (l&15)][kb*32 + (l>>4)*8 + e] )
__global__ __launch_bounds__(256) void build_Lp_kernel(const float* __restrict__ L,
                                                       __hip_bfloat16* __restrict__ Lp){
  __shared__ unsigned short tile[16][264];
  const int cb = blockIdx.x;   // 0..31
  const int rt = blockIdx.y;   // 0..511
  const int tid = threadIdx.x;
  #pragma unroll
  for (int i = 0; i < 4; ++i){
    int flat = i*256 + tid;
    int r  = flat >> 6;
    int c4 = flat & 63;
    float4 v = *(const float4*)(L + (long)(rt*16 + r)*N_ + cb*256 + c4*4);
    tile[r][c4*4+0] = __bfloat16_as_ushort(__float2bfloat16(v.x));
    tile[r][c4*4+1] = __bfloat16_as_ushort(__float2bfloat16(v.y));
    tile[r][c4*4+2] = __bfloat16_as_ushort(__float2bfloat16(v.z));
    tile[r][c4*4+3] = __bfloat16_as_ushort(__float2bfloat16(v.w));
  }
  __syncthreads();
  #pragma unroll
  for (int j = 0; j < 2; ++j){
    int flat = j*256 + tid;
    int kbl = flat >> 6;
    int l   = flat & 63;
    int lid = l & 15, g = l >> 4;
    uint4 frag = *(const uint4*)&tile[lid][kbl*32 + g*8];
    *(uint4*)(Lp + (((long)rt*256 + cb*8 + kbl)*64 + l)*8) = frag;
  }
}

// ---------------- prep: X (all t) and h0 -> bf16 frag-major (merged) ----------------
__global__ __launch_bounds__(256) void pack_xh_kernel(const float* __restrict__ X,
                                                      const float* __restrict__ H,
                                                      __hip_bfloat16* __restrict__ XTf,
                                                      __hip_bfloat16* __restrict__ hTf){
  if (blockIdx.x < 768){
    const int t = blockIdx.x >> 6;
    int flat = (blockIdx.x & 63)*256 + threadIdx.x;   // 0..16383
    int l = flat & 63, kb = flat >> 6;
    int lid = l & 15, g = l >> 4;
    int b = lid >> 3, f = lid & 7;
    int n0 = kb*32 + g*8;
    unsigned short u[8];
    #pragma unroll
    for (int e = 0; e < 8; ++e)
      u[e] = __bfloat16_as_ushort(__float2bfloat16(
          X[(((long)(b*T_ + t))*N_ + n0 + e)*FIN_ + f]));
    *(uint4*)(XTf + ((long)t*CGSZ + ((long)kb*64 + l)*8)) = *(uint4*)u;
  } else {
    int flat = (blockIdx.x - 768)*256 + threadIdx.x;  // 0..32767
    int l = flat & 63, kb = (flat >> 6) & 255, b = flat >> 14;
    int lid = l & 15, g = l >> 4;
    int n0 = kb*32 + g*8;
    unsigned short u[8];
    #pragma unroll
    for (int e = 0; e < 8; ++e)
      u[e] = __bfloat16_as_ushort(__float2bfloat16(
          H[((long)b*N_ + n0 + e)*HID_ + lid]));
    *(uint4*)(hTf + ((long)b*CGSZ + ((long)kb*64 + l)*8)) = *(uint4*)u;
  }
}

// ======== asm-pipelined MFMA core: dist-3, counted vmcnt, A=sc1 / B=cached ========
// voffsets are per-lane byte offsets into each stream's own buffer (32-bit, bounds-checked
// by num_records). Stage kk occupies buf index kk%3; steady outstanding = 2 stages (10 loads).
#define MM_ASM_CORE(rsA, voffA0_, voffA1_, rsB0, rsB1, rsB2, voffB_)             \
  f4v a00={0,0,0,0}, a01={0,0,0,0}, a02={0,0,0,0};                               \
  f4v a10={0,0,0,0}, a11={0,0,0,0}, a12={0,0,0,0};                               \
  s8v rA0[3], rA1[3], rB0[3], rB1[3], rB2[3];                                    \
  _Pragma("unroll")                                                              \
  for (int s = 0; s < 3; ++s){                                                   \
    BLOAD_A(rA0[s], rsA,  voffA0_ + s*1024u);                                    \
    BLOAD_A(rA1[s], rsA,  voffA1_ + s*1024u);                                    \
    BLOAD_B(rB0[s], rsB0, voffB_  + s*1024u);                                    \
    BLOAD_B(rB1[s], rsB1, voffB_  + s*1024u);                                    \
    BLOAD_B(rB2[s], rsB2, voffB_  + s*1024u);                                    \
  }                                                                              \
  _Pragma("unroll")                                                              \
  for (int kk = 0; kk < 32; ++kk){                                               \
    const int s = kk % 3;                                                        \
    if (kk < 30)      WAITV(10);                                                 \
    else if (kk == 30) WAITV(5);                                                 \
    else               WAITV(0);                                                 \
    s8v a0 = rA0[s], a1 = rA1[s], b0 = rB0[s], b1 = rB1[s], b2 = rB2[s];         \
    if (kk < 29){                                                                \
      BLOAD_A(rA0[s], rsA,  voffA0_ + (kk+3)*1024u);                             \
      BLOAD_A(rA1[s], rsA,  voffA1_ + (kk+3)*1024u);                             \
      BLOAD_B(rB0[s], rsB0, voffB_  + (kk+3)*1024u);                             \
      BLOAD_B(rB1[s], rsB1, voffB_  + (kk+3)*1024u);                             \
      BLOAD_B(rB2[s], rsB2, voffB_  + (kk+3)*1024u);                             \
    }                                                                            \
    a00 = MFMA16(a0,b0,a00); a01 = MFMA16(a0,b1,a01); a02 = MFMA16(a0,b2,a02);   \
    a10 = MFMA16(a1,b0,a10); a11 = MFMA16(a1,b1,a11); a12 = MFMA16(a1,b2,a12);   \
  }                                                                              \
  *(f4v*)&red[w][0][0][lane][0] = a00;                                           \
  *(f4v*)&red[w][0][1][lane][0] = a01;                                           \
  *(f4v*)&red[w][0][2][lane][0] = a02;                                           \
  *(f4v*)&red[w][1][0][lane][0] = a10;                                           \
  *(f4v*)&red[w][1][1][lane][0] = a11;                                           \
  *(f4v*)&red[w][1][2][lane][0] = a12;

// ---------------- pass 1: [u(32) | p(16)] = L @ [h | x_t]  (+ bf16 frag out) ----------------
__global__ __launch_bounds__(512) void mm_pass1_kernel(
    const __hip_bfloat16* __restrict__ Lp,
    const __hip_bfloat16* __restrict__ hTf,
    const __hip_bfloat16* __restrict__ XTft,
    __hip_bfloat16* __restrict__ y1f,
    float* __restrict__ u_, float* __restrict__ p_)
{
  __shared__ float red[8][2][3][64][4];   // 49152 B
  const int tid = threadIdx.x, w = tid >> 6, lane = tid & 63, blk = blockIdx.x;
  const int kb0 = w*32;

  const u32x4 rsA  = make_srsrc(Lp, 134217728u);         // 128 MiB
  const u32x4 rsB0 = make_srsrc(hTf, 262144u);           // 256 KiB each stream
  const u32x4 rsB1 = make_srsrc(hTf + CGSZ, 262144u);
  const u32x4 rsB2 = make_srsrc(XTft, 262144u);
  const unsigned voffA0 = (unsigned)((((blk*2+0)*256 + kb0)*64 + lane)*16);
  const unsigned voffA1 = (unsigned)((((blk*2+1)*256 + kb0)*64 + lane)*16);
  const unsigned voffB  = (unsigned)(((kb0)*64 + lane)*16);

  MM_ASM_CORE(rsA, voffA0, voffA1, rsB0, rsB1, rsB2, voffB)

  __syncthreads();
  for (int v = tid; v < 1536; v += 512){
    int rtl = (v >= 768) ? 1 : 0;
    int rem = v - rtl*768;
    int cgI = rem >> 8, r255 = rem & 255;
    int lid = r255 & 15, r = r255 >> 4;
    int g = r >> 2, j = r & 3;
    float s = 0.f;
    #pragma unroll
    for (int ww = 0; ww < 8; ++ww) s += red[ww][rtl][cgI][g*16 + lid][j];
    int n = blk*32 + rtl*16 + r;
    long o = (((long)cgI*256 + (n>>5))*64 + ((n>>3)&3)*16 + lid)*8 + (n&7);
    y1f[o] = __float2bfloat16(s);
    if (cgI < 2) u_[((long)cgI*N_ + n)*HID_ + lid] = s;
    else         p_[((long)(lid>>3)*N_ + n)*FIN_ + (lid&7)] = s;
  }
}

// ---------------- pass 2 + fused gates ----------------
__global__ __launch_bounds__(512) void mm_pass2_gate_kernel(
    const __hip_bfloat16* __restrict__ Lp,
    const __hip_bfloat16* __restrict__ y1f,
    const float* __restrict__ X,
    const float* __restrict__ H0, const float* __restrict__ C0,
    const float* __restrict__ Wx, const float* __restrict__ Wh,
    const float* __restrict__ bx, const float* __restrict__ bh,
    const float* __restrict__ wc, const float* __restrict__ bg,
    const float* __restrict__ u_, const float* __restrict__ p_,
    float* __restrict__ out, float* __restrict__ hs, float* __restrict__ cs,
    __hip_bfloat16* __restrict__ hTf, int t)
{
  __shared__ float red[8][2][3][64][4];   // 49152 B
  __shared__ float uv[48][32];            //  6144 B
  __shared__ float wlds[4848];            // 19392 B
  const int tid = threadIdx.x, w = tid >> 6, lane = tid & 63, blk = blockIdx.x;

  // stage gate weights BEFORE the asm pipeline (compiler-emitted loads+waits
  // complete here; sched_barrier pins them above the asm region).
  for (int i = tid; i < 1536; i += 512) wlds[i] = Wx[(long)t*1536 + i];
  for (int i = tid; i < 3072; i += 512) wlds[1536 + i] = Wh[(long)t*3072 + i];
  if (tid < 64){
    wlds[4608 + tid] = bx[t*64 + tid];
    wlds[4672 + tid] = bh[t*64 + tid];
    wlds[4736 + tid] = bg[t*64 + tid];
  }
  if (tid < 48) wlds[4800 + tid] = wc[t*48 + tid];
  __builtin_amdgcn_sched_barrier(0);

  const int kb0 = w*32;
  const u32x4 rsA  = make_srsrc(Lp, 134217728u);
  const u32x4 rsB0 = make_srsrc(y1f, 262144u);
  const u32x4 rsB1 = make_srsrc(y1f + CGSZ, 262144u);
  const u32x4 rsB2 = make_srsrc(y1f + 2*CGSZ, 262144u);
  const unsigned voffA0 = (unsigned)((((blk*2+0)*256 + kb0)*64 + lane)*16);
  const unsigned voffA1 = (unsigned)((((blk*2+1)*256 + kb0)*64 + lane)*16);
  const unsigned voffB  = (unsigned)(((kb0)*64 + lane)*16);

  MM_ASM_CORE(rsA, voffA0, voffA1, rsB0, rsB1, rsB2, voffB)

  __syncthreads();
  for (int v = tid; v < 1536; v += 512){
    int rtl = (v >= 768) ? 1 : 0;
    int rem = v - rtl*768;
    int cgI = rem >> 8, r255 = rem & 255;
    int lid = r255 & 15, r = r255 >> 4;
    int g = r >> 2, j = r & 3;
    float s = 0.f;
    #pragma unroll
    for (int ww = 0; ww < 8; ++ww) s += red[ww][rtl][cgI][g*16 + lid][j];
    uv[cgI*16 + lid][rtl*16 + r] = s;
  }
  __syncthreads();

  // gates: 1024 items (2 batch x 32 rows x 16 hid) over 512 threads
  #pragma unroll
  for (int it = 0; it < 2; ++it){
    int item = it*512 + tid;
    int gb = item >> 9, rr = (item >> 4) & 31, gh = item & 15;
    int n_g = blk*32 + rr;
    const float* xp = X + (((long)(gb*T_ + t))*N_ + n_g)*FIN_;
    const float* hp = (t==0) ? (H0 + ((long)gb*N_ + n_g)*HID_)
                             : (hs + (((long)(t-1)*B_ + gb)*N_ + n_g)*HID_);
    const float* cp = (t==0) ? (C0 + ((long)gb*N_ + n_g)*HID_)
                             : (cs + (((long)(t-1)*B_ + gb)*N_ + n_g)*HID_);
    const float* up = u_ + ((long)gb*N_ + n_g)*HID_;
    const float* pp = p_ + ((long)gb*N_ + n_g)*FIN_;

    float pre0 = wlds[4608 +  0 + gh] + wlds[4672 +  0 + gh] + wlds[4736 +  0 + gh];
    float pre1 = wlds[4608 + 16 + gh] + wlds[4672 + 16 + gh] + wlds[4736 + 16 + gh];
    float pre2 = wlds[4608 + 32 + gh] + wlds[4672 + 32 + gh] + wlds[4736 + 32 + gh];
    float pre3 = wlds[4608 + 48 + gh] + wlds[4672 + 48 + gh] + wlds[4736 + 48 + gh];
    #pragma unroll
    for (int f = 0; f < 8; ++f){
      float t0 = xp[f];
      float t1 = pp[f];
      float t2 = 2.f*uv[32 + gb*8 + f][rr] - t0;
      pre0 += t0*wlds[((0*3+0)*8+f)*16+gh] + t1*wlds[((0*3+1)*8+f)*16+gh] + t2*wlds[((0*3+2)*8+f)*16+gh];
      pre1 += t0*wlds[((1*3+0)*8+f)*16+gh] + t1*wlds[((1*3+1)*8+f)*16+gh] + t2*wlds[((1*3+2)*8+f)*16+gh];
      pre2 += t0*wlds[((2*3+0)*8+f)*16+gh] + t1*wlds[((2*3+1)*8+f)*16+gh] + t2*wlds[((2*3+2)*8+f)*16+gh];
      pre3 += t0*wlds[((3*3+0)*8+f)*16+gh] + t1*wlds[((3*3+1)*8+f)*16+gh] + t2*wlds[((3*3+2)*8+f)*16+gh];
    }
    #pragma unroll
    for (int j = 0; j < 16; ++j){
      float t0 = hp[j];
      float t1 = up[j];
      float t2 = 2.f*uv[gb*16 + j][rr] - t0;
      pre0 += t0*wlds[1536+((0*3+0)*16+j)*16+gh] + t1*wlds[1536+((0*3+1)*16+j)*16+gh] + t2*wlds[1536+((0*3+2)*16+j)*16+gh];
      pre1 += t0*wlds[1536+((1*3+0)*16+j)*16+gh] + t1*wlds[1536+((1*3+1)*16+j)*16+gh] + t2*wlds[1536+((1*3+2)*16+j)*16+gh];
      pre2 += t0*wlds[1536+((2*3+0)*16+j)*16+gh] + t1*wlds[1536+((2*3+1)*16+j)*16+gh] + t2*wlds[1536+((2*3+2)*16+j)*16+gh];
      pre3 += t0*wlds[1536+((3*3+0)*16+j)*16+gh] + t1*wlds[1536+((3*3+1)*16+j)*16+gh] + t2*wlds[1536+((3*3+2)*16+j)*16+gh];
    }
    float cc = cp[gh];
    float ig = sigmoidf_(pre0 + wlds[4800 +  0 + gh]*cc);
    float fg = sigmoidf_(pre1 + wlds[4800 + 16 + gh]*cc);
    float cnew = fg*cc + ig*tanhf(pre2);
    float og = sigmoidf_(pre3 + wlds[4800 + 32 + gh]*cnew);
    float hn = og*tanhf(cnew);
    hs [(((long)t*B_ + gb)*N_ + n_g)*HID_ + gh] = hn;
    cs [(((long)t*B_ + gb)*N_ + n_g)*HID_ + gh] = cnew;
    out[(((long)gb*T_ + t)*N_ + n_g)*HID_ + gh] = hn;
    const int kb = n_g >> 5, gg = (n_g >> 3) & 3, e = n_g & 7;
    hTf[(((long)gb*256 + kb)*64 + gg*16 + gh)*8 + e] = __float2bfloat16(hn);
  }
}

extern "C" void kernel_launch(void* const* d_in, const int* in_sizes, int n_in,
                              void* d_out, int out_size, void* d_ws, size_t ws_size,
                              hipStream_t stream)
{
  const float* X  = (const float*)d_in[0];
  const float* L  = (const float*)d_in[1];
  const float* H  = (const float*)d_in[2];
  const float* C  = (const float*)d_in[3];
  const float* Wx = (const float*)d_in[4];
  const float* Wh = (const float*)d_in[5];
  const float* bx = (const float*)d_in[6];
  const float* bh = (const float*)d_in[7];
  const float* wc = (const float*)d_in[8];
  const float* bg = (const float*)d_in[9];

  float* out = (float*)d_out;
  float* hs  = out + (long)B_*T_*N_*HID_;
  float* cs  = hs  + (long)T_*B_*N_*HID_;

  const size_t NEEDED = 140247040;
  if (ws_size < NEEDED) return;
  char* ws = (char*)d_ws;
  __hip_bfloat16* Lp  = (__hip_bfloat16*)(ws);                   // 128 MiB frag-major L
  __hip_bfloat16* XTf = (__hip_bfloat16*)(ws + 134217728);       // 3 MiB   [12][CGSZ]
  __hip_bfloat16* hTf = (__hip_bfloat16*)(ws + 137363456);       // 512 KiB [2][CGSZ]
  __hip_bfloat16* y1f = (__hip_bfloat16*)(ws + 137887744);       // 768 KiB [3][CGSZ]
  float* u_ = (float*)(ws + 138674176);                          // 1 MiB   [2][8192][16]
  float* p_ = (float*)(ws + 139722752);                          // 512 KiB [2][8192][8]

  build_Lp_kernel<<<dim3(32,512), 256, 0, stream>>>(L, Lp);
  pack_xh_kernel <<<896, 256, 0, stream>>>(X, H, XTf, hTf);

  for (int t = 0; t < T_; ++t){
    mm_pass1_kernel<<<256, 512, 0, stream>>>(Lp, hTf, XTf + (long)t*CGSZ,
                                             y1f, u_, p_);
    mm_pass2_gate_kernel<<<256, 512, 0, stream>>>(Lp, y1f, X, H, C,
                                                  Wx, Wh, bx, bh, wc, bg,
                                                  u_, p_, out, hs, cs, hTf, t);
  }
}